// Round 8
// baseline (164.358 us; speedup 1.0000x reference)
//
#include <hip/hip_runtime.h>
#include <cstddef>

// Problem constants (n=2, c=128, h=w=96, hid=256, P=5, heads=8, d_k=16)
constexpr int Cc = 128;
constexpr int Hh = 96;
constexpr int Ww = 96;
constexpr int HW = Hh * Ww;      // 9216 pixels per image
constexpr int Nn = 2;

typedef __attribute__((ext_vector_type(2))) _Float16 f16x2;
typedef __attribute__((ext_vector_type(4))) _Float16 f16x4;
typedef __attribute__((ext_vector_type(8))) _Float16 f16x8;
typedef __attribute__((ext_vector_type(4))) float f32x4;

__device__ __forceinline__ float fdot2(f16x2 a, f16x2 b, float c) {
#if defined(__has_builtin) && __has_builtin(__builtin_amdgcn_fdot2)
    return __builtin_amdgcn_fdot2(a, b, c, false);
#else
    return (float)a[0] * (float)b[0] + (float)a[1] * (float)b[1] + c;
#endif
}

// ---------------------------------------------------------------------------
// Weight fp32 -> f16 in MFMA B-FRAGMENT ORDER:
//   dst[((mt*(K/32) + kc)*64 + lane)*8 + j] = W[mt*16+(lane&15)][kc*32+(lane>>4)*8+j]
// Offsets (halves): wq 0, wk 16384, wv 32768, wfc 49152, w1 65536, w2 98304.
// ---------------------------------------------------------------------------
__global__ void __launch_bounds__(256)
wcvt_k(const float* __restrict__ wq, const float* __restrict__ wk,
       const float* __restrict__ wv, const float* __restrict__ wfc,
       const float* __restrict__ w1, const float* __restrict__ w2,
       _Float16* __restrict__ dst)
{
    const int h0 = (blockIdx.x * 256 + threadIdx.x) * 8;
    const float* src; int off, K;
    if (h0 < 16384)      { src = wq;  off = h0;          K = 128; }
    else if (h0 < 32768) { src = wk;  off = h0 - 16384;  K = 128; }
    else if (h0 < 49152) { src = wv;  off = h0 - 32768;  K = 128; }
    else if (h0 < 65536) { src = wfc; off = h0 - 49152;  K = 128; }
    else if (h0 < 98304) { src = w1;  off = h0 - 65536;  K = 128; }
    else                 { src = w2;  off = h0 - 98304;  K = 256; }
    const int fid  = off >> 3;
    const int lane = fid & 63;
    const int n16  = lane & 15, quad = lane >> 4;
    const int t2   = fid >> 6;
    const int kcN  = K / 32;
    const int kc   = t2 % kcN;
    const int mt   = t2 / kcN;
    const int row  = mt * 16 + n16;
    const int col  = kc * 32 + quad * 8;
    const float* s = src + (size_t)row * K + col;
    const float4 a = *(const float4*)s;
    const float4 b = *(const float4*)(s + 4);
    f16x8 h = {(_Float16)a.x, (_Float16)a.y, (_Float16)a.z, (_Float16)a.w,
               (_Float16)b.x, (_Float16)b.y, (_Float16)b.z, (_Float16)b.w};
    *(f16x8*)&dst[h0] = h;
}

// ---------------------------------------------------------------------------
// Fused k/v projections. X fp32 NCHW staged once to f16 k-major LDS;
// both 64-oc halves from the same tile (A-fragments hoisted and reused).
// Outputs f16 NHWC. grid (HW/64, 2, Nn), block 128.
// ---------------------------------------------------------------------------
__global__ void __launch_bounds__(128)
kv_k(const float* __restrict__ Xk, const float* __restrict__ Xv,
     const _Float16* __restrict__ w16,
     _Float16* __restrict__ k16, _Float16* __restrict__ v16)
{
    const int t  = blockIdx.y;
    const int p0 = blockIdx.x * 64;
    const int z  = blockIdx.z;
    const float* X = (t == 0) ? Xk : Xv;
    _Float16* Y    = (t == 0) ? k16 : v16;
    const _Float16* W = w16 + 16384 + (size_t)t * 16384;

    __shared__ _Float16 xl[128][72];   // [k][px]
    const int tid = threadIdx.x;
    {
        const int px4 = (tid & 15) * 4, kg = tid >> 4;
        const float* Xz = X + (size_t)z * Cc * HW + p0 + px4;
#pragma unroll
        for (int kk = 0; kk < 16; ++kk) {
            const int k = kk * 8 + kg;
            float4 a = *(const float4*)&Xz[(size_t)k * HW];
            f16x4 h = {(_Float16)a.x, (_Float16)a.y, (_Float16)a.z, (_Float16)a.w};
            *(f16x4*)&xl[k][px4] = h;
        }
    }
    __syncthreads();

    const int w = tid >> 6, lane = tid & 63;
    const int n16 = lane & 15, quad = lane >> 4;
    const int pw = w * 32;

    // hoisted A-fragments: independent of output-channel half
    f16x8 A[2][4];
#pragma unroll
    for (int mi = 0; mi < 2; ++mi) {
        const int px = pw + mi * 16 + n16;
#pragma unroll
        for (int kcid = 0; kcid < 4; ++kcid) {
            f16x8 av;
#pragma unroll
            for (int j = 0; j < 8; ++j) av[j] = xl[kcid * 32 + quad * 8 + j][px];
            A[mi][kcid] = av;
        }
    }

#pragma unroll
    for (int half = 0; half < 2; ++half) {
        const int oc0 = half * 64;
        f32x4 acc[2][4];
#pragma unroll
        for (int mi = 0; mi < 2; ++mi)
#pragma unroll
            for (int ni = 0; ni < 4; ++ni) acc[mi][ni] = (f32x4)0.f;

#pragma unroll
        for (int kcid = 0; kcid < 4; ++kcid) {
            f16x8 B[4];
#pragma unroll
            for (int ni = 0; ni < 4; ++ni)
                B[ni] = *(const f16x8*)&W[(((half * 4 + ni) * 4 + kcid) * 64 + lane) * 8];
#pragma unroll
            for (int mi = 0; mi < 2; ++mi)
#pragma unroll
                for (int ni = 0; ni < 4; ++ni)
                    acc[mi][ni] = __builtin_amdgcn_mfma_f32_16x16x32_f16(
                        A[mi][kcid], B[ni], acc[mi][ni], 0, 0, 0);
        }

#pragma unroll
        for (int mi = 0; mi < 2; ++mi)
#pragma unroll
            for (int r = 0; r < 4; ++r) {
                const int pix = p0 + pw + mi * 16 + quad * 4 + r;
                const size_t base = ((size_t)z * HW + pix) * Cc + oc0;
#pragma unroll
                for (int ni = 0; ni < 4; ++ni)
                    Y[base + ni * 16 + n16] = (_Float16)acc[mi][ni][r];
            }
    }
}

// ---------------------------------------------------------------------------
// FUSED q-proj + deformable attention + fc/MLP chain + GN partials.
// R4's proven 4 px/wave lane code in R6's fine grid: one block = 8 pixels,
// 128 thr = 2 waves. Grid 2304 blocks = 9/CU (fills the machine, no tail);
// LDS UNION cuts LDS to 12.5 KB (hl aliases dead xl+ql: 4096+4352=8448 B);
// VGPR ~88 (natural, no clamp -> no spills) caps 10 blocks/CU.
// M=16 MFMA with rows 8..15 = contained garbage (row m of A only affects
// row m of D through the whole chain); stores & GN partials gated quad<2.
//   phase 0 : stage X_q 8px x 128ch fp32 NCHW -> f16 [k][16] LDS
//   phase 0b: q = W_q @ x (wave w -> oc 64), q -> ql rows 0..15
//   phase 1 : attention, 4 px/wave (16 lanes/px, 8 ch/lane) — R4 body;
//             output overwrites ql rows 0..7 in place
//   phase 2 : fc -> y1l, mlp1 -> hl, y2 = y1 + w2@h + b2; fc accumulator
//             acc1 = fp32 residual (stage-1/3 lane maps identical)
// grid (HW/8, 1, Nn), block 128.
// ---------------------------------------------------------------------------
__global__ void __launch_bounds__(128)
qaf_k(const float* __restrict__ Xq, const _Float16* __restrict__ w16,
      const _Float16* __restrict__ k16, const _Float16* __restrict__ v16,
      const float* __restrict__ df, const float* __restrict__ b1,
      const float* __restrict__ b2, _Float16* __restrict__ y2,
      float* __restrict__ pb)
{
    __shared__ __align__(16) char smem[12800];
    __shared__ float red[4];
    auto xl  = (_Float16 (*)[16]) smem;             // [128][16]  4096 B
    auto ql  = (_Float16 (*)[136])(smem + 4096);    // [16][136]  4352 B
    auto y1l = (_Float16 (*)[136])(smem + 8448);    // [16][136]  4352 B
    auto hl  = (_Float16 (*)[264]) smem;            // [16][264]  8448 B = xl+ql

    const int z  = blockIdx.z;
    const int bx = blockIdx.x;
    const int ti = (bx & 7) * 144 + (bx >> 3);      // XCD swizzle (1152=8*144)
    const int p0 = ti * 8;
    const int tid = threadIdx.x, w = tid >> 6, lane = tid & 63;
    const int n16 = lane & 15, quad = lane >> 4;

    // ---- phase 0: stage X_q (8 px x 128 ch, fp32 NCHW -> f16 [k][px]) ----
    {
        const int px4 = (tid & 1) * 4, k0 = tid >> 1;   // k0 in 0..63
        const float* Xz = Xq + (size_t)z * Cc * HW + p0 + px4;
#pragma unroll
        for (int kk = 0; kk < 2; ++kk) {
            const int k = kk * 64 + k0;
            float4 a = *(const float4*)&Xz[(size_t)k * HW];
            f16x2 lo = {(_Float16)a.x, (_Float16)a.y};
            f16x2 hi = {(_Float16)a.z, (_Float16)a.w};
            *(f16x2*)&xl[k][px4]     = lo;
            *(f16x2*)&xl[k][px4 + 2] = hi;
        }
    }
    __syncthreads();

    // ---- phase 0b: q = W_q @ x  (M=16, rows 8..15 garbage; oc 64/wave) ----
    {
        f32x4 qa[4];
#pragma unroll
        for (int ni = 0; ni < 4; ++ni) qa[ni] = (f32x4)0.f;
#pragma unroll
        for (int kc = 0; kc < 4; ++kc) {
            f16x8 A;
#pragma unroll
            for (int j = 0; j < 8; ++j) A[j] = xl[kc * 32 + quad * 8 + j][n16];
#pragma unroll
            for (int ni = 0; ni < 4; ++ni) {
                const f16x8 B = *(const f16x8*)&w16[(((w * 4 + ni) * 4 + kc) * 64 + lane) * 8];
                qa[ni] = __builtin_amdgcn_mfma_f32_16x16x32_f16(A, B, qa[ni], 0, 0, 0);
            }
        }
#pragma unroll
        for (int ni = 0; ni < 4; ++ni)
#pragma unroll
            for (int r = 0; r < 4; ++r)
                ql[quad * 4 + r][w * 64 + ni * 16 + n16] = (_Float16)qa[ni][r];
    }
    __syncthreads();

    // ---- phase 1: deformable window attention (R4 body, 4 px/wave) ----
    {
        const int lpx = w * 4 + (lane >> 4);
        const int pix = p0 + lpx;
        const int y = pix / Ww, x = pix - y * Ww;
        const int co = n16 * 8;

        const float dx = df[((size_t)z * 2 + 0) * HW + pix];
        const float dy = df[((size_t)z * 2 + 1) * HW + pix];
        const float flx = floorf(dx), fly = floorf(dy);
        const int bxp = x - 2 + (int)flx;
        const int byp = y - 2 + (int)fly;
        const float wx1 = dx - flx, wx0 = 1.f - wx1;
        const float wy1 = dy - fly, wy0 = 1.f - wy1;
        const float s00 = wy0 * wx0 * 0.25f, s01 = wy0 * wx1 * 0.25f,
                    s10 = wy1 * wx0 * 0.25f, s11 = wy1 * wx1 * 0.25f;

        const f16x8 qv8 = *(const f16x8*)&ql[lpx][co];
        const f16x2 q0 = {qv8[0], qv8[1]}, q1 = {qv8[2], qv8[3]},
                    q2 = {qv8[4], qv8[5]}, q3 = {qv8[6], qv8[7]};

        const _Float16* kp = k16 + ((size_t)z * HW) * Cc + co;
        const _Float16* vp = v16 + ((size_t)z * HW) * Cc + co;

        const bool inb = (bxp >= 0) & (byp >= 0) & (bxp <= Ww - 6) & (byp <= Hh - 6);
        const int allin = __all(inb);

        float qk[36];
        if (allin) {
            const _Float16* kr = kp + (size_t)(byp * Ww + bxp) * Cc;
#pragma unroll
            for (int r = 0; r < 6; ++r) {
#pragma unroll
                for (int c = 0; c < 6; ++c) {
                    const f16x8 kv = *(const f16x8*)&kr[c * Cc];
                    f16x2 k0 = {kv[0], kv[1]}, k1 = {kv[2], kv[3]};
                    f16x2 k2 = {kv[4], kv[5]}, k3 = {kv[6], kv[7]};
                    float d = fdot2(q0, k0, 0.f);
                    d = fdot2(q1, k1, d);
                    d = fdot2(q2, k2, d);
                    d = fdot2(q3, k3, d);
                    qk[r * 6 + c] = d;
                }
                kr += Ww * Cc;
            }
        } else {
#pragma unroll
            for (int r = 0; r < 6; ++r) {
                const int yr = byp + r;
                const bool rv = (yr >= 0) & (yr < Hh);
                const int yc = min(max(yr, 0), Hh - 1);
                const _Float16* kr = kp + (size_t)(yc * Ww) * Cc;
#pragma unroll
                for (int c = 0; c < 6; ++c) {
                    const int xc = bxp + c;
                    const bool cv = rv & (xc >= 0) & (xc < Ww);
                    const int xcc = min(max(xc, 0), Ww - 1);
                    const f16x8 kv = *(const f16x8*)&kr[xcc * Cc];
                    f16x2 k0 = {kv[0], kv[1]}, k1 = {kv[2], kv[3]};
                    f16x2 k2 = {kv[4], kv[5]}, k3 = {kv[6], kv[7]};
                    float d = fdot2(q0, k0, 0.f);
                    d = fdot2(q1, k1, d);
                    d = fdot2(q2, k2, d);
                    d = fdot2(q3, k3, d);
                    qk[r * 6 + c] = cv ? d : 0.f;
                }
            }
        }

        float a[25];
#pragma unroll
        for (int py = 0; py < 5; ++py)
#pragma unroll
            for (int px = 0; px < 5; ++px) {
                float tv = s00 * qk[py * 6 + px];
                tv = fmaf(s01, qk[py * 6 + px + 1], tv);
                tv = fmaf(s10, qk[(py + 1) * 6 + px], tv);
                tv = fmaf(s11, qk[(py + 1) * 6 + px + 1], tv);
                a[py * 5 + px] = tv;
            }
#pragma unroll
        for (int i = 0; i < 25; ++i) a[i] += __shfl_xor(a[i], 1, 64);

        float mx = a[0];
#pragma unroll
        for (int i = 1; i < 25; ++i) mx = fmaxf(mx, a[i]);
        float ssum = 0.f;
#pragma unroll
        for (int i = 0; i < 25; ++i) { a[i] = __expf(a[i] - mx); ssum += a[i]; }
        const float inv = 1.f / ssum;

        // separable spread: rows (Wy) then cols (Wx)
        float tmp[6][5];
#pragma unroll
        for (int r = 0; r < 6; ++r)
#pragma unroll
            for (int px = 0; px < 5; ++px) {
                float tv = 0.f;
                if (r < 5)  tv = a[r * 5 + px] * wy0;
                if (r >= 1) tv = fmaf(a[(r - 1) * 5 + px], wy1, tv);
                tmp[r][px] = tv;
            }
        float wsum[36];
#pragma unroll
        for (int r = 0; r < 6; ++r)
#pragma unroll
            for (int c = 0; c < 6; ++c) {
                float tv = 0.f;
                if (c < 5)  tv = tmp[r][c] * wx0;
                if (c >= 1) tv = fmaf(tmp[r][c - 1], wx1, tv);
                wsum[r * 6 + c] = tv;
            }

        float o[8] = {0.f, 0.f, 0.f, 0.f, 0.f, 0.f, 0.f, 0.f};
        if (allin) {
            const _Float16* vr = vp + (size_t)(byp * Ww + bxp) * Cc;
#pragma unroll
            for (int r = 0; r < 6; ++r) {
#pragma unroll
                for (int c = 0; c < 6; ++c) {
                    const f16x8 vv = *(const f16x8*)&vr[c * Cc];
                    const float wgt = wsum[r * 6 + c];
#pragma unroll
                    for (int j = 0; j < 8; ++j)
                        o[j] = fmaf(wgt, (float)vv[j], o[j]);
                }
                vr += Ww * Cc;
            }
        } else {
#pragma unroll
            for (int r = 0; r < 6; ++r) {
                const int yr = byp + r;
                const bool rv = (yr >= 0) & (yr < Hh);
                const int yc = min(max(yr, 0), Hh - 1);
                const _Float16* vr = vp + (size_t)(yc * Ww) * Cc;
#pragma unroll
                for (int c = 0; c < 6; ++c) {
                    const int xc = bxp + c;
                    const bool cv = rv & (xc >= 0) & (xc < Ww);
                    const int xcc = min(max(xc, 0), Ww - 1);
                    const f16x8 vv = *(const f16x8*)&vr[xcc * Cc];
                    const float wgt = cv ? wsum[r * 6 + c] : 0.f;
#pragma unroll
                    for (int j = 0; j < 8; ++j)
                        o[j] = fmaf(wgt, (float)vv[j], o[j]);
                }
            }
        }

        f16x8 ov;
#pragma unroll
        for (int j = 0; j < 8; ++j) ov[j] = (_Float16)(o[j] * inv);
        *(f16x8*)&ql[lpx][co] = ov;   // in-place: rows are per-wave-private
    }
    __syncthreads();

    const _Float16* Wfc = w16 + 49152;
    const _Float16* W1  = w16 + 65536;
    const _Float16* W2  = w16 + 98304;

    // ---- stage 1: y1 = wfc @ attn  (M=16; wave w -> oc block w*64) ----
    f32x4 acc1[4];
#pragma unroll
    for (int ni = 0; ni < 4; ++ni) acc1[ni] = (f32x4)0.f;
#pragma unroll
    for (int kc = 0; kc < 4; ++kc) {
        const f16x8 A = *(const f16x8*)&ql[n16][kc * 32 + quad * 8];
#pragma unroll
        for (int ni = 0; ni < 4; ++ni) {
            const f16x8 B = *(const f16x8*)&Wfc[(((w * 4 + ni) * 4 + kc) * 64 + lane) * 8];
            acc1[ni] = __builtin_amdgcn_mfma_f32_16x16x32_f16(A, B, acc1[ni], 0, 0, 0);
        }
    }
#pragma unroll
    for (int ni = 0; ni < 4; ++ni)
#pragma unroll
        for (int r = 0; r < 4; ++r)
            y1l[quad * 4 + r][w * 64 + ni * 16 + n16] = (_Float16)acc1[ni][r];
    __syncthreads();

    // ---- stage 2: h = lrelu(w1 @ y1 + b1)  (M=16; wave w -> oc 128) ----
    {
        f32x4 acc2[8];
#pragma unroll
        for (int ni = 0; ni < 8; ++ni) acc2[ni] = (f32x4)0.f;
#pragma unroll
        for (int kc = 0; kc < 4; ++kc) {
            const f16x8 A = *(const f16x8*)&y1l[n16][kc * 32 + quad * 8];
#pragma unroll
            for (int ni = 0; ni < 8; ++ni) {
                const f16x8 B = *(const f16x8*)&W1[(((w * 8 + ni) * 4 + kc) * 64 + lane) * 8];
                acc2[ni] = __builtin_amdgcn_mfma_f32_16x16x32_f16(A, B, acc2[ni], 0, 0, 0);
            }
        }
        float b1v[8];
#pragma unroll
        for (int ni = 0; ni < 8; ++ni) b1v[ni] = b1[w * 128 + ni * 16 + n16];
#pragma unroll
        for (int ni = 0; ni < 8; ++ni)
#pragma unroll
            for (int r = 0; r < 4; ++r) {
                float tv = acc2[ni][r] + b1v[ni];
                tv = tv >= 0.f ? tv : 0.2f * tv;
                hl[quad * 4 + r][w * 128 + ni * 16 + n16] = (_Float16)tv;
            }
    }
    __syncthreads();

    // ---- stage 3: y2 = y1 + w2 @ h + b2  (M=16; wave w -> oc block w*64) --
    f32x4 acc3[4];
#pragma unroll
    for (int ni = 0; ni < 4; ++ni) acc3[ni] = (f32x4)0.f;
#pragma unroll
    for (int kc = 0; kc < 8; ++kc) {
        const f16x8 A = *(const f16x8*)&hl[n16][kc * 32 + quad * 8];
#pragma unroll
        for (int ni = 0; ni < 4; ++ni) {
            const f16x8 B = *(const f16x8*)&W2[(((w * 4 + ni) * 8 + kc) * 64 + lane) * 8];
            acc3[ni] = __builtin_amdgcn_mfma_f32_16x16x32_f16(A, B, acc3[ni], 0, 0, 0);
        }
    }

    float b2v[4];
#pragma unroll
    for (int ni = 0; ni < 4; ++ni) b2v[ni] = b2[w * 64 + ni * 16 + n16];

    float lsum = 0.f, lsq = 0.f;
    if (quad < 2) {
#pragma unroll
        for (int ni = 0; ni < 4; ++ni)
#pragma unroll
            for (int r = 0; r < 4; ++r) {
                const int pix = p0 + quad * 4 + r;
                const float tv = acc3[ni][r] + b2v[ni] + acc1[ni][r];
                lsum += tv; lsq += tv * tv;
                y2[((size_t)z * HW + pix) * Cc + w * 64 + ni * 16 + n16] = (_Float16)tv;
            }
    }

#pragma unroll
    for (int m = 1; m < 64; m <<= 1) {
        lsum += __shfl_xor(lsum, m, 64);
        lsq  += __shfl_xor(lsq,  m, 64);
    }
    if (lane == 0) { red[w * 2] = lsum; red[w * 2 + 1] = lsq; }
    __syncthreads();
    if (tid == 0) {
        const int bid = z * (HW / 8) + bx;
        pb[bid * 2 + 0] = red[0] + red[2];
        pb[bid * 2 + 1] = red[1] + red[3];
    }
}

// ---------------------------------------------------------------------------
// GroupNorm finalize + NHWC f16 -> NCHW fp32 transpose, with inline
// reduction of the per-block partials. grid (HW/64, Cc/32, Nn), block 256.
// ---------------------------------------------------------------------------
__global__ void __launch_bounds__(256)
gn_k(const _Float16* __restrict__ y2, const float* __restrict__ pb,
     const float* __restrict__ gamma, const float* __restrict__ beta,
     float* __restrict__ out, const int nPerZ)
{
    __shared__ float t[32][68];
    __shared__ float redm[8];
    __shared__ float stats[2];
    const int z = blockIdx.z, c0 = blockIdx.y * 32, p0 = blockIdx.x * 64;
    const int tid = threadIdx.x;

    // inline partial reduction (L2-hot, ~9 KB per z)
    {
        float s = 0.f, qq = 0.f;
        for (int p = tid; p < nPerZ; p += 256) {
            s  += pb[(z * nPerZ + p) * 2 + 0];
            qq += pb[(z * nPerZ + p) * 2 + 1];
        }
#pragma unroll
        for (int m = 1; m < 64; m <<= 1) {
            s  += __shfl_xor(s,  m, 64);
            qq += __shfl_xor(qq, m, 64);
        }
        if ((tid & 63) == 0) {
            redm[(tid >> 6) * 2]     = s;
            redm[(tid >> 6) * 2 + 1] = qq;
        }
    }
    // stage the transpose tile (f16 -> fp32)
    {
        const int px = tid >> 2, cq = tid & 3;
        const f16x8 a = *(const f16x8*)&y2[((size_t)z * HW + p0 + px) * Cc + c0 + cq * 8];
#pragma unroll
        for (int j = 0; j < 8; ++j) t[cq * 8 + j][px] = (float)a[j];
    }
    __syncthreads();
    if (tid == 0) {
        const float invN = 1.f / (float)(Cc * HW);
        const float S = redm[0] + redm[2] + redm[4] + redm[6];
        const float Q = redm[1] + redm[3] + redm[5] + redm[7];
        const float mean = S * invN;
        const float var  = fmaf(-mean, mean, Q * invN);
        stats[0] = mean;
        stats[1] = rsqrtf(var + 1e-5f);
    }
    __syncthreads();
    {
        const float mean = stats[0], rs = stats[1];
        const int c = tid >> 3, pq = tid & 7;
        const float g = gamma[c0 + c] * rs, be = beta[c0 + c];
        float4 o1, o2;
        o1.x = fmaf(t[c][pq * 8 + 0] - mean, g, be);
        o1.y = fmaf(t[c][pq * 8 + 1] - mean, g, be);
        o1.z = fmaf(t[c][pq * 8 + 2] - mean, g, be);
        o1.w = fmaf(t[c][pq * 8 + 3] - mean, g, be);
        o2.x = fmaf(t[c][pq * 8 + 4] - mean, g, be);
        o2.y = fmaf(t[c][pq * 8 + 5] - mean, g, be);
        o2.z = fmaf(t[c][pq * 8 + 6] - mean, g, be);
        o2.w = fmaf(t[c][pq * 8 + 7] - mean, g, be);
        float* dst = &out[((size_t)z * Cc + c0 + c) * HW + p0 + pq * 8];
        *(float4*)dst = o1;
        *(float4*)(dst + 4) = o2;
    }
}

// ---------------------------------------------------------------------------
extern "C" void kernel_launch(void* const* d_in, const int* in_sizes, int n_in,
                              void* d_out, int out_size, void* d_ws, size_t ws_size,
                              hipStream_t stream)
{
    const float* query  = (const float*)d_in[0];
    const float* key    = (const float*)d_in[1];
    const float* value  = (const float*)d_in[2];
    const float* deform = (const float*)d_in[3];
    const float* w_q    = (const float*)d_in[4];
    const float* w_k    = (const float*)d_in[5];
    const float* w_v    = (const float*)d_in[6];
    const float* w_fc   = (const float*)d_in[7];
    const float* mlp_w1 = (const float*)d_in[8];
    const float* mlp_b1 = (const float*)d_in[9];
    const float* mlp_w2 = (const float*)d_in[10];
    const float* mlp_b2 = (const float*)d_in[11];
    const float* gn_g   = (const float*)d_in[12];
    const float* gn_b   = (const float*)d_in[13];
    float* out = (float*)d_out;

    // workspace layout
    char* wsb = (char*)d_ws;
    _Float16* w16 = (_Float16*)wsb;                  // 131072 halves, frag order
    float* pb   = (float*)(wsb + 262144);            // per-block partials (2304*2)
    _Float16* T = (_Float16*)(wsb + 524288);
    const size_t S16 = (size_t)Nn * HW * Cc;         // halves per f16 tensor
    _Float16* k16  = T;                              // R0
    _Float16* v16  = T + S16;                        // R1
    _Float16* y2h  = T + 2 * S16;                    // R2 (f16 NHWC)

    // weights -> f16 fragment order
    wcvt_k<<<dim3(64), dim3(256), 0, stream>>>(
        w_q, w_k, w_v, w_fc, mlp_w1, mlp_w2, w16);

    // fused k/v projections -> f16 NHWC
    kv_k<<<dim3(HW / 64, 2, Nn), dim3(128), 0, stream>>>(
        key, value, w16, k16, v16);

    // fused q-proj + attention + fc/mlp chain -> f16 NHWC y2 + GN partials
    qaf_k<<<dim3(HW / 8, 1, Nn), dim3(128), 0, stream>>>(
        query, w16, k16, v16, deform, mlp_b1, mlp_b2, y2h, pb);

    // GroupNorm finalize (inline partial reduce) + NHWC->NCHW
    gn_k<<<dim3(HW / 64, Cc / 32, Nn), dim3(256), 0, stream>>>(
        y2h, pb, gn_g, gn_b, out, HW / 8);
}

// Round 9
// 140.640 us; speedup vs baseline: 1.1686x; 1.1686x over previous
//
#include <hip/hip_runtime.h>
#include <cstddef>

// Problem constants (n=2, c=128, h=w=96, hid=256, P=5, heads=8, d_k=16)
constexpr int Cc = 128;
constexpr int Hh = 96;
constexpr int Ww = 96;
constexpr int HW = Hh * Ww;      // 9216 pixels per image
constexpr int Nn = 2;

typedef __attribute__((ext_vector_type(2))) _Float16 f16x2;
typedef __attribute__((ext_vector_type(4))) _Float16 f16x4;
typedef __attribute__((ext_vector_type(8))) _Float16 f16x8;
typedef __attribute__((ext_vector_type(4))) float f32x4;

__device__ __forceinline__ float fdot2(f16x2 a, f16x2 b, float c) {
#if defined(__has_builtin) && __has_builtin(__builtin_amdgcn_fdot2)
    return __builtin_amdgcn_fdot2(a, b, c, false);
#else
    return (float)a[0] * (float)b[0] + (float)a[1] * (float)b[1] + c;
#endif
}

// ---------------------------------------------------------------------------
// Weight fp32 -> f16 in MFMA B-FRAGMENT ORDER:
//   dst[((mt*(K/32) + kc)*64 + lane)*8 + j] = W[mt*16+(lane&15)][kc*32+(lane>>4)*8+j]
// Offsets (halves): wq 0, wk 16384, wv 32768, wfc 49152, w1 65536, w2 98304.
// ---------------------------------------------------------------------------
__global__ void __launch_bounds__(256)
wcvt_k(const float* __restrict__ wq, const float* __restrict__ wk,
       const float* __restrict__ wv, const float* __restrict__ wfc,
       const float* __restrict__ w1, const float* __restrict__ w2,
       _Float16* __restrict__ dst)
{
    const int h0 = (blockIdx.x * 256 + threadIdx.x) * 8;
    const float* src; int off, K;
    if (h0 < 16384)      { src = wq;  off = h0;          K = 128; }
    else if (h0 < 32768) { src = wk;  off = h0 - 16384;  K = 128; }
    else if (h0 < 49152) { src = wv;  off = h0 - 32768;  K = 128; }
    else if (h0 < 65536) { src = wfc; off = h0 - 49152;  K = 128; }
    else if (h0 < 98304) { src = w1;  off = h0 - 65536;  K = 128; }
    else                 { src = w2;  off = h0 - 98304;  K = 256; }
    const int fid  = off >> 3;
    const int lane = fid & 63;
    const int n16  = lane & 15, quad = lane >> 4;
    const int t2   = fid >> 6;
    const int kcN  = K / 32;
    const int kc   = t2 % kcN;
    const int mt   = t2 / kcN;
    const int row  = mt * 16 + n16;
    const int col  = kc * 32 + quad * 8;
    const float* s = src + (size_t)row * K + col;
    const float4 a = *(const float4*)s;
    const float4 b = *(const float4*)(s + 4);
    f16x8 h = {(_Float16)a.x, (_Float16)a.y, (_Float16)a.z, (_Float16)a.w,
               (_Float16)b.x, (_Float16)b.y, (_Float16)b.z, (_Float16)b.w};
    *(f16x8*)&dst[h0] = h;
}

// ---------------------------------------------------------------------------
// Fused k/v projections. X fp32 NCHW staged once to f16 k-major LDS;
// both 64-oc halves from the same tile (A-fragments hoisted and reused).
// Outputs f16 NHWC. grid (HW/64, 2, Nn), block 128.
// ---------------------------------------------------------------------------
__global__ void __launch_bounds__(128)
kv_k(const float* __restrict__ Xk, const float* __restrict__ Xv,
     const _Float16* __restrict__ w16,
     _Float16* __restrict__ k16, _Float16* __restrict__ v16)
{
    const int t  = blockIdx.y;
    const int p0 = blockIdx.x * 64;
    const int z  = blockIdx.z;
    const float* X = (t == 0) ? Xk : Xv;
    _Float16* Y    = (t == 0) ? k16 : v16;
    const _Float16* W = w16 + 16384 + (size_t)t * 16384;

    __shared__ _Float16 xl[128][72];   // [k][px]
    const int tid = threadIdx.x;
    {
        const int px4 = (tid & 15) * 4, kg = tid >> 4;
        const float* Xz = X + (size_t)z * Cc * HW + p0 + px4;
#pragma unroll
        for (int kk = 0; kk < 16; ++kk) {
            const int k = kk * 8 + kg;
            float4 a = *(const float4*)&Xz[(size_t)k * HW];
            f16x4 h = {(_Float16)a.x, (_Float16)a.y, (_Float16)a.z, (_Float16)a.w};
            *(f16x4*)&xl[k][px4] = h;
        }
    }
    __syncthreads();

    const int w = tid >> 6, lane = tid & 63;
    const int n16 = lane & 15, quad = lane >> 4;
    const int pw = w * 32;

    // hoisted A-fragments: independent of output-channel half
    f16x8 A[2][4];
#pragma unroll
    for (int mi = 0; mi < 2; ++mi) {
        const int px = pw + mi * 16 + n16;
#pragma unroll
        for (int kcid = 0; kcid < 4; ++kcid) {
            f16x8 av;
#pragma unroll
            for (int j = 0; j < 8; ++j) av[j] = xl[kcid * 32 + quad * 8 + j][px];
            A[mi][kcid] = av;
        }
    }

#pragma unroll
    for (int half = 0; half < 2; ++half) {
        const int oc0 = half * 64;
        f32x4 acc[2][4];
#pragma unroll
        for (int mi = 0; mi < 2; ++mi)
#pragma unroll
            for (int ni = 0; ni < 4; ++ni) acc[mi][ni] = (f32x4)0.f;

#pragma unroll
        for (int kcid = 0; kcid < 4; ++kcid) {
            f16x8 B[4];
#pragma unroll
            for (int ni = 0; ni < 4; ++ni)
                B[ni] = *(const f16x8*)&W[(((half * 4 + ni) * 4 + kcid) * 64 + lane) * 8];
#pragma unroll
            for (int mi = 0; mi < 2; ++mi)
#pragma unroll
                for (int ni = 0; ni < 4; ++ni)
                    acc[mi][ni] = __builtin_amdgcn_mfma_f32_16x16x32_f16(
                        A[mi][kcid], B[ni], acc[mi][ni], 0, 0, 0);
        }

#pragma unroll
        for (int mi = 0; mi < 2; ++mi)
#pragma unroll
            for (int r = 0; r < 4; ++r) {
                const int pix = p0 + pw + mi * 16 + quad * 4 + r;
                const size_t base = ((size_t)z * HW + pix) * Cc + oc0;
#pragma unroll
                for (int ni = 0; ni < 4; ++ni)
                    Y[base + ni * 16 + n16] = (_Float16)acc[mi][ni][r];
            }
    }
}

// ---------------------------------------------------------------------------
// FUSED q-proj + deformable attention + fc/MLP chain + GN partials.
// R4 structure (empirically optimal: 16 px/block, 256 thr = 4 waves,
// 4 px/wave, ~22 KB LDS, natural VGPR) + register diet in the attention
// phase: QK rows stream into a[25] via rolling qkP/qkC (peak 37 vs 61 live)
// and the separable spread folds into the PV loop as per-row tr[5]
// (peak 38 vs 69 live). Arithmetic identical to R4; VGPR ~88 -> ~76.
//   phase 0 : stage X_q tile fp32 NCHW -> f16 [k][px] LDS (stride 18)
//   phase 0b: q = W_q @ x via MFMA (wave w -> 32-oc block), q -> ql LDS
//   phase 1 : attention, 4 px/wave (16 lanes/px, 8 ch/lane), row-streamed
//   phase 2 : fc -> y1l, mlp1 -> hl, y2 = y1 + w2@h + b2; fc accumulator
//             acc1 = fp32 residual (stage-1/3 lane maps identical)
// Epilogue: f16 NHWC y2 + per-block GN partials.
// grid (HW/16, 1, Nn), block 256.
// ---------------------------------------------------------------------------
__global__ void __launch_bounds__(256)
qaf_k(const float* __restrict__ Xq, const _Float16* __restrict__ w16,
      const _Float16* __restrict__ k16, const _Float16* __restrict__ v16,
      const float* __restrict__ df, const float* __restrict__ b1,
      const float* __restrict__ b2, _Float16* __restrict__ y2,
      float* __restrict__ pb)
{
    __shared__ __align__(16) _Float16 xl[128][18];    // X_q staging [k][px]
    __shared__ __align__(16) _Float16 ql[16][140];    // q, then attn output
    __shared__ __align__(16) _Float16 y1l[16][140];
    __shared__ __align__(16) _Float16 hl[16][264];
    __shared__ float red[8];

    const int z  = blockIdx.z;
    const int bx = blockIdx.x;
    const int ti = (bx & 7) * 72 + (bx >> 3);          // XCD swizzle (576=8*72)
    const int p0 = ti * 16;
    const int tid = threadIdx.x, w = tid >> 6, lane = tid & 63;
    const int n16 = lane & 15, quad = lane >> 4;

    // ---- phase 0: stage X_q (16 px x 128 ch, fp32 NCHW -> f16 [k][px]) ----
    {
        const int px4 = (tid & 3) * 4, k0 = tid >> 2;  // k0 in 0..63
        const float* Xz = Xq + (size_t)z * Cc * HW + p0 + px4;
#pragma unroll
        for (int kk = 0; kk < 2; ++kk) {
            const int k = kk * 64 + k0;
            float4 a = *(const float4*)&Xz[(size_t)k * HW];
            f16x2 lo = {(_Float16)a.x, (_Float16)a.y};
            f16x2 hi = {(_Float16)a.z, (_Float16)a.w};
            *(f16x2*)&xl[k][px4]     = lo;
            *(f16x2*)&xl[k][px4 + 2] = hi;
        }
    }
    __syncthreads();

    // ---- phase 0b: q = W_q @ x  (wave w -> oc block w*32) ----
    {
        f32x4 qa[2];
        qa[0] = (f32x4)0.f; qa[1] = (f32x4)0.f;
#pragma unroll
        for (int kc = 0; kc < 4; ++kc) {
            f16x8 A;
#pragma unroll
            for (int j = 0; j < 8; ++j) A[j] = xl[kc * 32 + quad * 8 + j][n16];
#pragma unroll
            for (int ni = 0; ni < 2; ++ni) {
                const f16x8 B = *(const f16x8*)&w16[(((w * 2 + ni) * 4 + kc) * 64 + lane) * 8];
                qa[ni] = __builtin_amdgcn_mfma_f32_16x16x32_f16(A, B, qa[ni], 0, 0, 0);
            }
        }
#pragma unroll
        for (int ni = 0; ni < 2; ++ni)
#pragma unroll
            for (int r = 0; r < 4; ++r)
                ql[quad * 4 + r][w * 32 + ni * 16 + n16] = (_Float16)qa[ni][r];
    }
    __syncthreads();

    // ---- phase 1: attention (wave w -> px w*4+(lane>>4); 8 ch/lane) ----
    {
        const int lpx = w * 4 + (lane >> 4);
        const int pix = p0 + lpx;
        const int y = pix / Ww, x = pix - y * Ww;
        const int co = n16 * 8;

        const float dx = df[((size_t)z * 2 + 0) * HW + pix];
        const float dy = df[((size_t)z * 2 + 1) * HW + pix];
        const float flx = floorf(dx), fly = floorf(dy);
        const int bxp = x - 2 + (int)flx;
        const int byp = y - 2 + (int)fly;
        const float wx1 = dx - flx, wx0 = 1.f - wx1;
        const float wy1 = dy - fly, wy0 = 1.f - wy1;
        const float s00 = wy0 * wx0 * 0.25f, s01 = wy0 * wx1 * 0.25f,
                    s10 = wy1 * wx0 * 0.25f, s11 = wy1 * wx1 * 0.25f;

        const f16x8 qv8 = *(const f16x8*)&ql[lpx][co];
        const f16x2 q0 = {qv8[0], qv8[1]}, q1 = {qv8[2], qv8[3]},
                    q2 = {qv8[4], qv8[5]}, q3 = {qv8[6], qv8[7]};

        const _Float16* kp = k16 + ((size_t)z * HW) * Cc + co;
        const _Float16* vp = v16 + ((size_t)z * HW) * Cc + co;

        const bool inb = (bxp >= 0) & (byp >= 0) & (bxp <= Ww - 6) & (byp <= Hh - 6);
        const int allin = __all(inb);

        // QK row-streamed into a[25] (rolling qkP/qkC keeps live state low)
        float a[25];
        {
            float qkP[6], qkC[6];
            if (allin) {
                const _Float16* kr = kp + (size_t)(byp * Ww + bxp) * Cc;
#pragma unroll
                for (int r = 0; r < 6; ++r) {
#pragma unroll
                    for (int c = 0; c < 6; ++c) {
                        const f16x8 kv = *(const f16x8*)&kr[c * Cc];
                        f16x2 k0 = {kv[0], kv[1]}, k1 = {kv[2], kv[3]};
                        f16x2 k2 = {kv[4], kv[5]}, k3 = {kv[6], kv[7]};
                        float d = fdot2(q0, k0, 0.f);
                        d = fdot2(q1, k1, d);
                        d = fdot2(q2, k2, d);
                        qkC[c] = fdot2(q3, k3, d);
                    }
                    if (r >= 1) {
#pragma unroll
                        for (int px = 0; px < 5; ++px) {
                            float tv = s00 * qkP[px];
                            tv = fmaf(s01, qkP[px + 1], tv);
                            tv = fmaf(s10, qkC[px], tv);
                            tv = fmaf(s11, qkC[px + 1], tv);
                            a[(r - 1) * 5 + px] = tv;
                        }
                    }
#pragma unroll
                    for (int c = 0; c < 6; ++c) qkP[c] = qkC[c];
                    kr += Ww * Cc;
                }
            } else {
#pragma unroll
                for (int r = 0; r < 6; ++r) {
                    const int yr = byp + r;
                    const bool rv = (yr >= 0) & (yr < Hh);
                    const int yc = min(max(yr, 0), Hh - 1);
                    const _Float16* kr = kp + (size_t)(yc * Ww) * Cc;
#pragma unroll
                    for (int c = 0; c < 6; ++c) {
                        const int xc = bxp + c;
                        const bool cv = rv & (xc >= 0) & (xc < Ww);
                        const int xcc = min(max(xc, 0), Ww - 1);
                        const f16x8 kv = *(const f16x8*)&kr[xcc * Cc];
                        f16x2 k0 = {kv[0], kv[1]}, k1 = {kv[2], kv[3]};
                        f16x2 k2 = {kv[4], kv[5]}, k3 = {kv[6], kv[7]};
                        float d = fdot2(q0, k0, 0.f);
                        d = fdot2(q1, k1, d);
                        d = fdot2(q2, k2, d);
                        d = fdot2(q3, k3, d);
                        qkC[c] = cv ? d : 0.f;
                    }
                    if (r >= 1) {
#pragma unroll
                        for (int px = 0; px < 5; ++px) {
                            float tv = s00 * qkP[px];
                            tv = fmaf(s01, qkP[px + 1], tv);
                            tv = fmaf(s10, qkC[px], tv);
                            tv = fmaf(s11, qkC[px + 1], tv);
                            a[(r - 1) * 5 + px] = tv;
                        }
                    }
#pragma unroll
                    for (int c = 0; c < 6; ++c) qkP[c] = qkC[c];
                }
            }
        }

        // head reduce: 16 ch = 2 lanes (lane bit 0)
#pragma unroll
        for (int i = 0; i < 25; ++i) a[i] += __shfl_xor(a[i], 1, 64);

        float mx = a[0];
#pragma unroll
        for (int i = 1; i < 25; ++i) mx = fmaxf(mx, a[i]);
        float ssum = 0.f;
#pragma unroll
        for (int i = 0; i < 25; ++i) { a[i] = __expf(a[i] - mx); ssum += a[i]; }
        const float inv = 1.f / ssum;

        // PV with the separable spread folded in row-wise (tr[5] per row)
        float o[8] = {0.f, 0.f, 0.f, 0.f, 0.f, 0.f, 0.f, 0.f};
        if (allin) {
            const _Float16* vr = vp + (size_t)(byp * Ww + bxp) * Cc;
#pragma unroll
            for (int r = 0; r < 6; ++r) {
                float tr[5];
#pragma unroll
                for (int px = 0; px < 5; ++px) {
                    float tv = 0.f;
                    if (r < 5)  tv = a[r * 5 + px] * wy0;
                    if (r >= 1) tv = fmaf(a[(r - 1) * 5 + px], wy1, tv);
                    tr[px] = tv;
                }
#pragma unroll
                for (int c = 0; c < 6; ++c) {
                    float wgt = 0.f;
                    if (c < 5)  wgt = tr[c] * wx0;
                    if (c >= 1) wgt = fmaf(tr[c - 1], wx1, wgt);
                    const f16x8 vv = *(const f16x8*)&vr[c * Cc];
#pragma unroll
                    for (int j = 0; j < 8; ++j)
                        o[j] = fmaf(wgt, (float)vv[j], o[j]);
                }
                vr += Ww * Cc;
            }
        } else {
#pragma unroll
            for (int r = 0; r < 6; ++r) {
                float tr[5];
#pragma unroll
                for (int px = 0; px < 5; ++px) {
                    float tv = 0.f;
                    if (r < 5)  tv = a[r * 5 + px] * wy0;
                    if (r >= 1) tv = fmaf(a[(r - 1) * 5 + px], wy1, tv);
                    tr[px] = tv;
                }
                const int yr = byp + r;
                const bool rv = (yr >= 0) & (yr < Hh);
                const int yc = min(max(yr, 0), Hh - 1);
                const _Float16* vr = vp + (size_t)(yc * Ww) * Cc;
#pragma unroll
                for (int c = 0; c < 6; ++c) {
                    const int xc = bxp + c;
                    const bool cv = rv & (xc >= 0) & (xc < Ww);
                    const int xcc = min(max(xc, 0), Ww - 1);
                    float wgt = 0.f;
                    if (c < 5)  wgt = tr[c] * wx0;
                    if (c >= 1) wgt = fmaf(tr[c - 1], wx1, wgt);
                    wgt = cv ? wgt : 0.f;
                    const f16x8 vv = *(const f16x8*)&vr[xcc * Cc];
#pragma unroll
                    for (int j = 0; j < 8; ++j)
                        o[j] = fmaf(wgt, (float)vv[j], o[j]);
                }
            }
        }

        f16x8 ov;
#pragma unroll
        for (int j = 0; j < 8; ++j) ov[j] = (_Float16)(o[j] * inv);
        *(f16x8*)&ql[lpx][co] = ov;   // in-place: rows are per-wave-private
    }
    __syncthreads();

    const _Float16* Wfc = w16 + 49152;
    const _Float16* W1  = w16 + 65536;
    const _Float16* W2  = w16 + 98304;

    // ---- stage 1: y1 = wfc @ attn  (wave w -> oc block w*32) ----
    f32x4 acc1[2];
    acc1[0] = (f32x4)0.f; acc1[1] = (f32x4)0.f;
#pragma unroll
    for (int kc = 0; kc < 4; ++kc) {
        const f16x8 A = *(const f16x8*)&ql[n16][kc * 32 + quad * 8];
#pragma unroll
        for (int ni = 0; ni < 2; ++ni) {
            const f16x8 B = *(const f16x8*)&Wfc[(((w * 2 + ni) * 4 + kc) * 64 + lane) * 8];
            acc1[ni] = __builtin_amdgcn_mfma_f32_16x16x32_f16(A, B, acc1[ni], 0, 0, 0);
        }
    }
#pragma unroll
    for (int ni = 0; ni < 2; ++ni)
#pragma unroll
        for (int r = 0; r < 4; ++r)
            y1l[quad * 4 + r][w * 32 + ni * 16 + n16] = (_Float16)acc1[ni][r];
    __syncthreads();

    // ---- stage 2: h = lrelu(w1 @ y1 + b1)  (wave w -> oc block w*64) ----
    {
        f32x4 acc2[4];
#pragma unroll
        for (int ni = 0; ni < 4; ++ni) acc2[ni] = (f32x4)0.f;
#pragma unroll
        for (int kc = 0; kc < 4; ++kc) {
            const f16x8 A = *(const f16x8*)&y1l[n16][kc * 32 + quad * 8];
#pragma unroll
            for (int ni = 0; ni < 4; ++ni) {
                const f16x8 B = *(const f16x8*)&W1[(((w * 4 + ni) * 4 + kc) * 64 + lane) * 8];
                acc2[ni] = __builtin_amdgcn_mfma_f32_16x16x32_f16(A, B, acc2[ni], 0, 0, 0);
            }
        }
        float b1v[4];
#pragma unroll
        for (int ni = 0; ni < 4; ++ni) b1v[ni] = b1[w * 64 + ni * 16 + n16];
#pragma unroll
        for (int ni = 0; ni < 4; ++ni)
#pragma unroll
            for (int r = 0; r < 4; ++r) {
                float tv = acc2[ni][r] + b1v[ni];
                tv = tv >= 0.f ? tv : 0.2f * tv;
                hl[quad * 4 + r][w * 64 + ni * 16 + n16] = (_Float16)tv;
            }
    }
    __syncthreads();

    // ---- stage 3: y2 = y1 + w2 @ h + b2  (wave w -> oc block w*32) ----
    f32x4 acc3[2];
    acc3[0] = (f32x4)0.f; acc3[1] = (f32x4)0.f;
#pragma unroll
    for (int kc = 0; kc < 8; ++kc) {
        const f16x8 A = *(const f16x8*)&hl[n16][kc * 32 + quad * 8];
#pragma unroll
        for (int ni = 0; ni < 2; ++ni) {
            const f16x8 B = *(const f16x8*)&W2[(((w * 2 + ni) * 8 + kc) * 64 + lane) * 8];
            acc3[ni] = __builtin_amdgcn_mfma_f32_16x16x32_f16(A, B, acc3[ni], 0, 0, 0);
        }
    }

    float b2v[2];
#pragma unroll
    for (int ni = 0; ni < 2; ++ni) b2v[ni] = b2[w * 32 + ni * 16 + n16];

    float lsum = 0.f, lsq = 0.f;
#pragma unroll
    for (int ni = 0; ni < 2; ++ni)
#pragma unroll
        for (int r = 0; r < 4; ++r) {
            const int pix = p0 + quad * 4 + r;
            const float tv = acc3[ni][r] + b2v[ni] + acc1[ni][r];
            lsum += tv; lsq += tv * tv;
            y2[((size_t)z * HW + pix) * Cc + w * 32 + ni * 16 + n16] = (_Float16)tv;
        }

#pragma unroll
    for (int m = 1; m < 64; m <<= 1) {
        lsum += __shfl_xor(lsum, m, 64);
        lsq  += __shfl_xor(lsq,  m, 64);
    }
    if (lane == 0) { red[w * 2] = lsum; red[w * 2 + 1] = lsq; }
    __syncthreads();
    if (tid == 0) {
        float S = 0.f, Q = 0.f;
#pragma unroll
        for (int i = 0; i < 4; ++i) { S += red[i * 2]; Q += red[i * 2 + 1]; }
        const int bid = z * (HW / 16) + bx;
        pb[bid * 2 + 0] = S;
        pb[bid * 2 + 1] = Q;
    }
}

// ---------------------------------------------------------------------------
// GroupNorm finalize + NHWC f16 -> NCHW fp32 transpose, with inline
// reduction of the per-block partials. grid (HW/64, Cc/32, Nn), block 256.
// ---------------------------------------------------------------------------
__global__ void __launch_bounds__(256)
gn_k(const _Float16* __restrict__ y2, const float* __restrict__ pb,
     const float* __restrict__ gamma, const float* __restrict__ beta,
     float* __restrict__ out, const int nPerZ)
{
    __shared__ float t[32][68];
    __shared__ float redm[8];
    __shared__ float stats[2];
    const int z = blockIdx.z, c0 = blockIdx.y * 32, p0 = blockIdx.x * 64;
    const int tid = threadIdx.x;

    // inline partial reduction (L2-hot, ~4.6 KB per z)
    {
        float s = 0.f, qq = 0.f;
        for (int p = tid; p < nPerZ; p += 256) {
            s  += pb[(z * nPerZ + p) * 2 + 0];
            qq += pb[(z * nPerZ + p) * 2 + 1];
        }
#pragma unroll
        for (int m = 1; m < 64; m <<= 1) {
            s  += __shfl_xor(s,  m, 64);
            qq += __shfl_xor(qq, m, 64);
        }
        if ((tid & 63) == 0) {
            redm[(tid >> 6) * 2]     = s;
            redm[(tid >> 6) * 2 + 1] = qq;
        }
    }
    // stage the transpose tile (f16 -> fp32)
    {
        const int px = tid >> 2, cq = tid & 3;
        const f16x8 a = *(const f16x8*)&y2[((size_t)z * HW + p0 + px) * Cc + c0 + cq * 8];
#pragma unroll
        for (int j = 0; j < 8; ++j) t[cq * 8 + j][px] = (float)a[j];
    }
    __syncthreads();
    if (tid == 0) {
        const float invN = 1.f / (float)(Cc * HW);
        const float S = redm[0] + redm[2] + redm[4] + redm[6];
        const float Q = redm[1] + redm[3] + redm[5] + redm[7];
        const float mean = S * invN;
        const float var  = fmaf(-mean, mean, Q * invN);
        stats[0] = mean;
        stats[1] = rsqrtf(var + 1e-5f);
    }
    __syncthreads();
    {
        const float mean = stats[0], rs = stats[1];
        const int c = tid >> 3, pq = tid & 7;
        const float g = gamma[c0 + c] * rs, be = beta[c0 + c];
        float4 o1, o2;
        o1.x = fmaf(t[c][pq * 8 + 0] - mean, g, be);
        o1.y = fmaf(t[c][pq * 8 + 1] - mean, g, be);
        o1.z = fmaf(t[c][pq * 8 + 2] - mean, g, be);
        o1.w = fmaf(t[c][pq * 8 + 3] - mean, g, be);
        o2.x = fmaf(t[c][pq * 8 + 4] - mean, g, be);
        o2.y = fmaf(t[c][pq * 8 + 5] - mean, g, be);
        o2.z = fmaf(t[c][pq * 8 + 6] - mean, g, be);
        o2.w = fmaf(t[c][pq * 8 + 7] - mean, g, be);
        float* dst = &out[((size_t)z * Cc + c0 + c) * HW + p0 + pq * 8];
        *(float4*)dst = o1;
        *(float4*)(dst + 4) = o2;
    }
}

// ---------------------------------------------------------------------------
extern "C" void kernel_launch(void* const* d_in, const int* in_sizes, int n_in,
                              void* d_out, int out_size, void* d_ws, size_t ws_size,
                              hipStream_t stream)
{
    const float* query  = (const float*)d_in[0];
    const float* key    = (const float*)d_in[1];
    const float* value  = (const float*)d_in[2];
    const float* deform = (const float*)d_in[3];
    const float* w_q    = (const float*)d_in[4];
    const float* w_k    = (const float*)d_in[5];
    const float* w_v    = (const float*)d_in[6];
    const float* w_fc   = (const float*)d_in[7];
    const float* mlp_w1 = (const float*)d_in[8];
    const float* mlp_b1 = (const float*)d_in[9];
    const float* mlp_w2 = (const float*)d_in[10];
    const float* mlp_b2 = (const float*)d_in[11];
    const float* gn_g   = (const float*)d_in[12];
    const float* gn_b   = (const float*)d_in[13];
    float* out = (float*)d_out;

    // workspace layout
    char* wsb = (char*)d_ws;
    _Float16* w16 = (_Float16*)wsb;                  // 131072 halves, frag order
    float* pb   = (float*)(wsb + 262144);            // per-block partials (1152*2)
    _Float16* T = (_Float16*)(wsb + 524288);
    const size_t S16 = (size_t)Nn * HW * Cc;         // halves per f16 tensor
    _Float16* k16  = T;                              // R0
    _Float16* v16  = T + S16;                        // R1
    _Float16* y2h  = T + 2 * S16;                    // R2 (f16 NHWC)

    // weights -> f16 fragment order
    wcvt_k<<<dim3(64), dim3(256), 0, stream>>>(
        w_q, w_k, w_v, w_fc, mlp_w1, mlp_w2, w16);

    // fused k/v projections -> f16 NHWC
    kv_k<<<dim3(HW / 64, 2, Nn), dim3(128), 0, stream>>>(
        key, value, w16, k16, v16);

    // fused q-proj + attention + fc/mlp chain -> f16 NHWC y2 + GN partials
    qaf_k<<<dim3(HW / 16, 1, Nn), dim3(256), 0, stream>>>(
        query, w16, k16, v16, deform, mlp_b1, mlp_b2, y2h, pb);

    // GroupNorm finalize (inline partial reduce) + NHWC->NCHW
    gn_k<<<dim3(HW / 64, Cc / 32, Nn), dim3(256), 0, stream>>>(
        y2h, pb, gn_g, gn_b, out, HW / 16);
}